// Round 1
// baseline (203.024 us; speedup 1.0000x reference)
//
#include <hip/hip_runtime.h>

#define N_USER 100000
#define N_ITEM 50000
#define NTOT   150000
#define D      64
#define NNZ    4000000
#define B      2048
#define NEG    8192
#define NSLOT  (B + B + NEG)   /* 12288 output rows */

// ---------------------------------------------------------------------------
// Kernel 1: clear the "row needed" flags (ws is poisoned 0xAA every call)
// ---------------------------------------------------------------------------
__global__ void k_clear_flags(unsigned char* __restrict__ flag) {
    int i = blockIdx.x * blockDim.x + threadIdx.x;
    if (i < NTOT) flag[i] = 0;
}

__device__ __forceinline__ int slot_row(int slot,
                                        const int* __restrict__ users,
                                        const int* __restrict__ pos,
                                        const int* __restrict__ neg) {
    if (slot < B)     return users[slot];
    if (slot < 2 * B) return N_USER + pos[slot - B];
    return N_USER + neg[slot - 2 * B];
}

// ---------------------------------------------------------------------------
// Kernel 2: mark needed rows, zero their accumulator rows (one wave / slot).
// Duplicate rows race benignly (all write the same values).
// ---------------------------------------------------------------------------
__global__ void k_mark(const int* __restrict__ users,
                       const int* __restrict__ pos,
                       const int* __restrict__ neg,
                       unsigned char* __restrict__ flag,
                       float* __restrict__ acc) {
    int wave = (blockIdx.x * blockDim.x + threadIdx.x) >> 6;
    int lane = threadIdx.x & 63;
    if (wave >= NSLOT) return;
    int r = slot_row(wave, users, pos, neg);
    acc[(size_t)r * D + lane] = 0.0f;
    if (lane == 0) flag[r] = 1;
}

// ---------------------------------------------------------------------------
// Kernel 3: filtered SpMM. Each wave takes 64 consecutive nnz: coalesced
// loads of row/col/val, ballot on flag[row], then for each hit the whole
// wave (lane = dim) gathers e0[col] and atomically accumulates into acc[row].
// ---------------------------------------------------------------------------
__global__ void k_spmm(const int*   __restrict__ adj_row,
                       const int*   __restrict__ adj_col,
                       const float* __restrict__ adj_val,
                       const float* __restrict__ ue,
                       const float* __restrict__ ie,
                       const unsigned char* __restrict__ flag,
                       float* __restrict__ acc) {
    int lane   = threadIdx.x & 63;
    int wave   = (blockIdx.x * blockDim.x + threadIdx.x) >> 6;
    int nwaves = (gridDim.x * blockDim.x) >> 6;

    for (long long base = (long long)wave * 64; base < NNZ;
         base += (long long)nwaves * 64) {
        int e = (int)base + lane;
        int r = 0, c = 0;
        float v = 0.0f;
        bool ok = (e < NNZ);
        if (ok) r = adj_row[e];
        bool need = ok && (flag[r] != 0);
        unsigned long long m = __ballot(need);
        if (!m) continue;
        if (ok) { c = adj_col[e]; v = adj_val[e]; }
        while (m) {
            int l = __builtin_ctzll(m);
            m &= m - 1;
            int   rr = __shfl(r, l);
            int   cc = __shfl(c, l);
            float vv = __shfl(v, l);
            float x  = (cc < N_USER) ? ue[(size_t)cc * D + lane]
                                     : ie[(size_t)(cc - N_USER) * D + lane];
            atomicAdd(&acc[(size_t)rr * D + lane], vv * x);
        }
    }
}

// ---------------------------------------------------------------------------
// Kernel 4: gather outputs: out[slot] = 0.25*e0[r] + 0.75*acc[r]
// (light_out = (e0 + LAYERS*ae0)/(LAYERS+1), LAYERS=3)
// ---------------------------------------------------------------------------
__global__ void k_out(const int* __restrict__ users,
                      const int* __restrict__ pos,
                      const int* __restrict__ neg,
                      const float* __restrict__ ue,
                      const float* __restrict__ ie,
                      const float* __restrict__ acc,
                      float* __restrict__ out) {
    int wave = (blockIdx.x * blockDim.x + threadIdx.x) >> 6;
    int lane = threadIdx.x & 63;
    if (wave >= NSLOT) return;
    int r = slot_row(wave, users, pos, neg);
    float e = (r < N_USER) ? ue[(size_t)r * D + lane]
                           : ie[(size_t)(r - N_USER) * D + lane];
    out[(size_t)wave * D + lane] = 0.25f * e + 0.75f * acc[(size_t)r * D + lane];
}

// ---------------------------------------------------------------------------
extern "C" void kernel_launch(void* const* d_in, const int* in_sizes, int n_in,
                              void* d_out, int out_size, void* d_ws, size_t ws_size,
                              hipStream_t stream) {
    const int*   users   = (const int*)  d_in[0];
    const int*   pos     = (const int*)  d_in[1];
    const int*   neg     = (const int*)  d_in[2];
    // d_in[3] mask, d_in[4] norm_adj: unused placeholders
    const float* ue      = (const float*)d_in[5];
    const float* ie      = (const float*)d_in[6];
    const int*   adj_row = (const int*)  d_in[7];
    const int*   adj_col = (const int*)  d_in[8];
    const float* adj_val = (const float*)d_in[9];
    float*       out     = (float*)      d_out;

    float*         acc  = (float*)d_ws;                       // [NTOT, D] f32
    unsigned char* flag = (unsigned char*)d_ws +
                          (size_t)NTOT * D * sizeof(float);   // [NTOT] bytes

    k_clear_flags<<<(NTOT + 255) / 256, 256, 0, stream>>>(flag);
    k_mark<<<(NSLOT * 64 + 255) / 256, 256, 0, stream>>>(users, pos, neg, flag, acc);
    k_spmm<<<2048, 256, 0, stream>>>(adj_row, adj_col, adj_val, ue, ie, flag, acc);
    k_out<<<(NSLOT * 64 + 255) / 256, 256, 0, stream>>>(users, pos, neg, ue, ie, acc, out);
}